// Round 17
// baseline (248.945 us; speedup 1.0000x reference)
//
#include <hip/hip_runtime.h>
#include <hip/hip_bf16.h>
#include <math.h>

// Shapes: B=2, S=2048, H=1024, nh=16, hd=64. Inputs f32, outputs f32.
// d_out = [out: 2*2048*1024] ++ [attn: 2*16*2048*2048], both f32.
// exp2-domain softmax, no running max. Attn (R16): QBLK=128 (8 waves),
// K LDS-staged both passes, bf16 bias, P 2-slot LDS + in-loop NT flush,
// mask-free fast path + setprio, complementary qt pairing.
// This round: QKV GEMM epilogue LDS-staged -> fully-coalesced bx8 stores.

typedef __attribute__((ext_vector_type(8))) short bx8;   // 8 bf16 (4 VGPRs)
typedef __attribute__((ext_vector_type(4))) short sx4;   // 4 bf16
typedef __attribute__((ext_vector_type(4))) float fx4;   // MFMA accum
typedef __attribute__((ext_vector_type(4))) float f4v;

#define MFMA_BF16(a, b, c) __builtin_amdgcn_mfma_f32_16x16x32_bf16(a, b, c, 0, 0, 0)
#define LOG2E 1.44269504088896340736f

__device__ __forceinline__ short f2bf(float f) {
    union { float f; unsigned u; } v; v.f = f;
    unsigned u = v.u;
    u += 0x7fffu + ((u >> 16) & 1u);   // RTNE
    return (short)(u >> 16);
}
__device__ __forceinline__ float u2f(unsigned u) {
    union { unsigned u; float f; } v; v.u = u; return v.f;
}
__device__ __forceinline__ float bf2f(short s) {
    return u2f(((unsigned)(unsigned short)s) << 16);
}

__device__ __forceinline__ bx8 pack8(f4v a, f4v b) {
    bx8 r;
    r[0] = f2bf(a[0]); r[1] = f2bf(a[1]); r[2] = f2bf(a[2]); r[3] = f2bf(a[3]);
    r[4] = f2bf(b[0]); r[5] = f2bf(b[1]); r[6] = f2bf(b[2]); r[7] = f2bf(b[3]);
    return r;
}

__device__ __forceinline__ void gload_lds16(const short* g, short* l) {
    __builtin_amdgcn_global_load_lds(
        (const __attribute__((address_space(1))) void*)g,
        (__attribute__((address_space(3))) void*)l, 16, 0, 0);
}

// ---------------- cast: blocks 0..4095 -> bf16 of [x:4M][Wq..Wo:4x1M];
//                  blocks 4096..6143 -> bias_bf = bf16(bias * log2e)
__global__ __launch_bounds__(256) void cast_kernel(
        const float* __restrict__ x, const float* __restrict__ Wq,
        const float* __restrict__ Wk, const float* __restrict__ Wv,
        const float* __restrict__ Wo, const float* __restrict__ bias,
        short* __restrict__ dst, short* __restrict__ bias_bf)
{
    const size_t M1 = 1u << 20;
    if (blockIdx.x < 4096) {
        const size_t e0 = ((size_t)blockIdx.x * 256 + threadIdx.x) * 8;
        const float* src; size_t off;
        if (e0 < 4 * M1) { src = x; off = e0; }
        else {
            const int j = (int)((e0 - 4 * M1) >> 20);
            src = (j == 0) ? Wq : (j == 1) ? Wk : (j == 2) ? Wv : Wo;
            off = (e0 - 4 * M1) & (M1 - 1);
        }
        f4v a = *(const f4v*)(src + off);
        f4v b = *(const f4v*)(src + off + 4);
        *(bx8*)(dst + e0) = pack8(a, b);
    } else {
        const size_t e0 = ((size_t)(blockIdx.x - 4096) * 256 + threadIdx.x) * 8;
        f4v a = *(const f4v*)(bias + e0);
        f4v b = *(const f4v*)(bias + e0 + 4);
        #pragma unroll
        for (int i = 0; i < 4; ++i) { a[i] *= LOG2E; b[i] *= LOG2E; }
        *(bx8*)(bias_bf + e0) = pack8(a, b);
    }
}

// ---------------- RoPE cos/sin table: [2048][64] f32 each ----------------
__global__ void rope_table_kernel(float* __restrict__ cosT, float* __restrict__ sinT) {
    int i = blockIdx.x * 256 + threadIdx.x;
    if (i >= 2048 * 64) return;
    int s = i >> 6, d = i & 63;
    int fi = d & 31;                               // emb = concat(freqs, freqs)
    float inv_freq = powf(10000.0f, -(float)fi / 32.0f);
    float ang = (float)s * inv_freq;
    cosT[i] = cosf(ang);
    sinT[i] = sinf(ang);
}

// ---------------- GEMM 128x128, BK=64, global_load_lds + XOR chunk swizzle.
// OUTPROJ=0: RoPE epilogue staged through LDS (Cs aliases As/Bs) -> bx8
//            fully-coalesced stores to [bh][s][d] bf16.
// OUTPROJ=1: plain f32 row-major epilogue (direct stores).
template<int OUTPROJ>
__global__ __launch_bounds__(256) void gemm128(
        const short* __restrict__ A, const short* __restrict__ W0,
        const short* __restrict__ W1, const short* __restrict__ W2,
        const float* __restrict__ cosT, const float* __restrict__ sinT,
        void* __restrict__ Out)
{
    __shared__ __align__(16) char SMEM[128 * 130 * 2];   // 33280 B
    short (*As)[64]  = (short(*)[64])SMEM;               // 16 KB
    short (*Bs)[64]  = (short(*)[64])(SMEM + 16384);     // 16 KB
    short (*Cs)[130] = (short(*)[130])SMEM;              // epilogue alias

    const int bm = blockIdx.x, bn = blockIdx.y, z = blockIdx.z;
    const short* W = OUTPROJ ? W0 : (z == 0 ? W0 : (z == 1 ? W1 : W2));
    const int tid = threadIdx.x, w = tid >> 6, lane = tid & 63;
    const int cl = lane & 15, lg = lane >> 4;
    const int srow = lane >> 3;
    const int schunk = (lane & 7) ^ srow;

    fx4 acc[4][4];
    #pragma unroll
    for (int mi = 0; mi < 4; ++mi)
        #pragma unroll
        for (int ni = 0; ni < 4; ++ni) acc[mi][ni] = (fx4){0.f, 0.f, 0.f, 0.f};

    const int wr = (w >> 1) * 64, wc = (w & 1) * 64;

    for (int k0 = 0; k0 < 1024; k0 += 64) {
        __syncthreads();
        #pragma unroll
        for (int i = 0; i < 4; ++i) {
            const int rbase = w * 32 + i * 8;
            gload_lds16(A + (size_t)(bm * 128 + rbase + srow) * 1024 + k0 + schunk * 8,
                        &As[rbase][0]);
            gload_lds16(W + (size_t)(bn * 128 + rbase + srow) * 1024 + k0 + schunk * 8,
                        &Bs[rbase][0]);
        }
        __syncthreads();
        #pragma unroll
        for (int kk = 0; kk < 2; ++kk) {
            bx8 af[4], bf[4];
            #pragma unroll
            for (int i = 0; i < 4; ++i) {
                const int ra = wr + i * 16 + cl;
                af[i] = *(const bx8*)&As[ra][((kk * 4 + lg) ^ (ra & 7)) * 8];
                const int rb = wc + i * 16 + cl;
                bf[i] = *(const bx8*)&Bs[rb][((kk * 4 + lg) ^ (rb & 7)) * 8];
            }
            #pragma unroll
            for (int mi = 0; mi < 4; ++mi)
                #pragma unroll
                for (int ni = 0; ni < 4; ++ni)
                    acc[mi][ni] = MFMA_BF16(af[mi], bf[ni], acc[mi][ni]);
        }
    }

    if constexpr (OUTPROJ) {
        #pragma unroll
        for (int mi = 0; mi < 4; ++mi) {
            #pragma unroll
            for (int reg = 0; reg < 4; ++reg) {
                const int r = bm * 128 + wr + mi * 16 + (lg << 2) + reg;
                #pragma unroll
                for (int ni = 0; ni < 4; ++ni) {
                    const int col = bn * 128 + wc + ni * 16 + cl;
                    ((float*)Out)[(size_t)r * 1024 + col] = acc[mi][ni][reg];
                }
            }
        }
    } else {
        __syncthreads();                    // all waves done reading As/Bs
        #pragma unroll
        for (int mi = 0; mi < 4; ++mi) {
            #pragma unroll
            for (int reg = 0; reg < 4; ++reg) {
                const int rl = wr + mi * 16 + (lg << 2) + reg;   // local row
                const int s = (bm * 128 + rl) & 2047;
                #pragma unroll
                for (int ni = 0; ni < 4; ++ni) {
                    const int cloc = wc + ni * 16 + cl;          // local col
                    const int d = cloc & 63;
                    float v = acc[mi][ni][reg];
                    if (z <= 1) {
                        const float cs = cosT[s * 64 + d], sn = sinT[s * 64 + d];
                        const float partner = acc[mi][ni ^ 2][reg];   // d ^ 32
                        const float rot = (d < 32) ? -partner : partner;
                        v = v * cs + rot * sn;
                        if (z == 0) v *= 0.125f * LOG2E;   // scale+exp2 fold into q
                    }
                    Cs[rl][cloc] = f2bf(v);
                }
            }
        }
        __syncthreads();                    // Cs complete
        // coalesced store: 2048 units of (s_local, h, 16B-chunk); 8 per thread.
        // Each wave-store = 8 x 128B fully-utilized segments.
        #pragma unroll
        for (int i = 0; i < 8; ++i) {
            const int u = tid + i * 256;
            const int chunk = u & 7, hh = (u >> 3) & 1, sl = u >> 4;
            bx8 vv = *(const bx8*)&Cs[sl][hh * 64 + chunk * 8];
            const int r = bm * 128 + sl;
            const int bb = r >> 11, ss = r & 2047;
            short* dst = (short*)Out + (size_t)z * 32 * 2048 * 64
                       + (size_t)((bb * 16 + bn * 2 + hh) * 2048 + ss) * 64 + chunk * 8;
            *(bx8*)dst = vv;
        }
    }
}

// ---------------- Attention (byte-identical to R16) ----------------
__global__ __launch_bounds__(512, 4) void attn_kernel(
        const short* __restrict__ Q, const short* __restrict__ K,
        const short* __restrict__ V, const short* __restrict__ bias_bf,
        float* __restrict__ attn_out, short* __restrict__ o_buf)
{
    const int S = 2048;
    const int bid = blockIdx.x;                    // 0..511
    const int bh = (bid & 7) * 4 + ((bid >> 3) & 3);   // same for bid, bid+256
    const int qt = (bid < 256) ? (15 - (bid >> 5)) : ((bid >> 5) - 8);
    const int h = bh & 15, b = bh >> 4;
    const int tid = threadIdx.x, w = tid >> 6, lane = tid & 63;
    const int cl = lane & 15, lg = lane >> 4;
    const size_t base = (size_t)bh * S * 64;
    const int NT = 2 * qt + 2;                     // always even

    __shared__ short Ks[2][64][64];    // K tile [kc][d], XOR-chunk swizzled
    __shared__ short Vt[2][64][72];    // V^T tile [d][kc]
    __shared__ short P[8][16][136];    // per-wave P, 2 tile-slots

    const int krow8 = lane >> 3, kchk = (lane & 7) ^ krow8;
    const int vrow = tid >> 3, vd0 = (tid & 7) * 8;

    const short* qp = Q + base + (size_t)(qt * 128 + w * 16 + cl) * 64 + lg * 8;
    const bx8 qf0 = *(const bx8*)qp;
    const bx8 qf1 = *(const bx8*)(qp + 32);
    const int qr  = qt * 128 + w * 16 + cl;          // lane's q row
    const int qrmin = qt * 128 + w * 16;             // wave's min q row
    const int sq0 = qt * 128 + w * 16 + (lg << 2);   // lane's first O row
    const short* brow = bias_bf + (size_t)qr * 2048;
    const size_t strip_base = ((size_t)bh * S + qt * 128 + w * 16) * S;

#define STAGEK(BUF, t)                                                            \
    gload_lds16(K + base + (size_t)((t) * 64 + w * 8 + krow8) * 64 + kchk * 8,    \
                &Ks[BUF][w * 8][0]);

#define LOADB(BR, t)                                                              \
    { _Pragma("unroll") for (int n = 0; n < 4; ++n)                               \
        BR[n] = *(const sx4*)(brow + (t) * 64 + n * 16 + (lg << 2)); }

#define QKT(BUF, SACC)                                                            \
    { const int cs_ = cl & 7;                                                     \
      const fx4 zf = (fx4){0.f, 0.f, 0.f, 0.f};                                   \
      __builtin_amdgcn_s_setprio(1);                                              \
      _Pragma("unroll") for (int n = 0; n < 4; ++n) {                             \
        bx8 a0 = *(const bx8*)&Ks[BUF][n * 16 + cl][(lg ^ cs_) * 8];              \
        bx8 a1 = *(const bx8*)&Ks[BUF][n * 16 + cl][((4 + lg) ^ cs_) * 8];        \
        SACC[n] = MFMA_BF16(a0, qf0, zf);                                         \
        SACC[n] = MFMA_BF16(a1, qf1, SACC[n]); }                                  \
      __builtin_amdgcn_s_setprio(0); }

#define COMP_A(BUF, BR, t)                                                        \
    { fx4 sacc[4]; QKT(BUF, sacc);                                                \
      if ((t) * 64 + 63 <= qrmin) {               /* fully causal: no mask */     \
        _Pragma("unroll") for (int n = 0; n < 4; ++n)                             \
          _Pragma("unroll") for (int e = 0; e < 4; ++e)                           \
            lsum[n] += exp2f(sacc[n][e] + bf2f(BR[n][e]));                        \
      } else {                                                                    \
        _Pragma("unroll") for (int n = 0; n < 4; ++n)                             \
          _Pragma("unroll") for (int e = 0; e < 4; ++e) {                         \
            const int kc = (t) * 64 + n * 16 + (lg << 2) + e;                     \
            const float sv = sacc[n][e] + bf2f(BR[n][e]);                         \
            lsum[n] += (kc <= qr) ? exp2f(sv) : 0.f; }                            \
      } }

#define LOADVr(V0, t)                                                             \
    V0 = *(const bx8*)(V + base + (size_t)((t) * 64 + vrow) * 64 + vd0);

#define VSTORE(V0, BUF)                                                           \
    { _Pragma("unroll") for (int j = 0; j < 8; ++j) Vt[BUF][vd0 + j][vrow] = V0[j]; }

#define COMP_B(KBUF, BR, VBUF, t)                                                 \
    { fx4 sacc[4]; QKT(KBUF, sacc);                                               \
      if ((t) * 64 + 63 <= qrmin) {               /* fully causal: no mask */     \
        _Pragma("unroll") for (int n = 0; n < 4; ++n) {                           \
          sx4 pb;                                                                 \
          _Pragma("unroll") for (int e = 0; e < 4; ++e)                           \
            pb[e] = f2bf(exp2f(sacc[n][e] + bf2f(BR[n][e]) - L2));                \
          *(sx4*)&P[w][cl][((t) & 1) * 64 + n * 16 + (lg << 2)] = pb; }           \
      } else {                                                                    \
        _Pragma("unroll") for (int n = 0; n < 4; ++n) {                           \
          sx4 pb;                                                                 \
          _Pragma("unroll") for (int e = 0; e < 4; ++e) {                         \
            const int kc = (t) * 64 + n * 16 + (lg << 2) + e;                     \
            const float sv = sacc[n][e] + bf2f(BR[n][e]);                         \
            const float p = (kc <= qr) ? exp2f(sv - L2) : 0.f;                    \
            pb[e] = f2bf(p); }                                                    \
          *(sx4*)&P[w][cl][((t) & 1) * 64 + n * 16 + (lg << 2)] = pb; }           \
      }                                                                           \
      __builtin_amdgcn_s_setprio(1);                                              \
      _Pragma("unroll") for (int kk = 0; kk < 2; ++kk) {                          \
        bx8 pa = *(const bx8*)&P[w][cl][((t) & 1) * 64 + kk * 32 + lg * 8];       \
        _Pragma("unroll") for (int n = 0; n < 4; ++n) {                           \
          bx8 vb = *(const bx8*)&Vt[VBUF][n * 16 + cl][kk * 32 + lg * 8];         \
          oacc[n] = MFMA_BF16(pa, vb, oacc[n]); } }                               \
      __builtin_amdgcn_s_setprio(0); }

#define FLUSH2(tp)                                                                \
    { _Pragma("unroll") for (int rp = 0; rp < 16; rp += 2) {                      \
        const int row = rp + (lane >> 5), col = (lane & 31) * 4;                  \
        const unsigned* ps = (const unsigned*)&P[w][row][col];                    \
        const unsigned px = ps[0], py = ps[1];                                    \
        f4v o; o[0] = u2f(px << 16); o[1] = u2f(px & 0xffff0000u);                \
        o[2] = u2f(py << 16); o[3] = u2f(py & 0xffff0000u);                       \
        __builtin_nontemporal_store(o,                                            \
            (f4v*)(attn_out + strip_base + (size_t)row * S + (tp) * 64 + col)); } }

    float lsum[4] = {0.f, 0.f, 0.f, 0.f};

    // ---- PASS A: l = sum exp2(s2+bias); staged K, NT even -> no tail ----
    {
        sx4 bA[4], bB[4];
        STAGEK(0, 0); LOADB(bA, 0);
        __syncthreads();
        for (int t = 0; t + 1 < NT; t += 2) {
            STAGEK(1, t + 1); LOADB(bB, t + 1);
            COMP_A(0, bA, t);
            __syncthreads();
            if (t + 2 < NT) { STAGEK(0, t + 2); LOADB(bA, t + 2); }
            COMP_A(1, bB, t + 1);
            __syncthreads();
        }
    }

    float l = (lsum[0] + lsum[1]) + (lsum[2] + lsum[3]);
    l += __shfl_xor(l, 16);
    l += __shfl_xor(l, 32);
    const float L2 = __log2f(l);

    fx4 oacc[4];
    #pragma unroll
    for (int n = 0; n < 4; n++) oacc[n] = (fx4){0.f, 0.f, 0.f, 0.f};

    // ---- PASS B ----
    sx4 bA[4], bB[4];
    bx8 vA0, vB0;
    STAGEK(0, 0); LOADB(bA, 0); LOADVr(vA0, 0);
    __syncthreads();                   // Ks[0] staged (pass A readers done too)
    VSTORE(vA0, 0);
    __syncthreads();                   // Vt[0] visible
    for (int t = 0; t + 1 < NT; t += 2) {
        STAGEK(1, t + 1); LOADB(bB, t + 1); LOADVr(vB0, t + 1);
        COMP_B(0, bA, 0, t);
        VSTORE(vB0, 1);
        __syncthreads();
        if (t + 2 < NT) { STAGEK(0, t + 2); LOADB(bA, t + 2); LOADVr(vA0, t + 2); }
        COMP_B(1, bB, 1, t + 1);
        FLUSH2(t);                     // wave-local P -> attn, cols t*64..t*64+127
        if (t + 2 < NT) VSTORE(vA0, 0);
        __syncthreads();
    }

    // write O tile to o_buf[b][s][h*64+d] (bf16; re-read by outproj)
    #pragma unroll
    for (int reg = 0; reg < 4; reg++) {
        const int sq = sq0 + reg;
        #pragma unroll
        for (int n = 0; n < 4; n++) {
            const int d = n * 16 + cl;
            o_buf[(size_t)(b * 2048 + sq) * 1024 + h * 64 + d] = f2bf(oacc[n][reg]);
        }
    }

    // zero-fill strict upper triangle (k >= (qt+1)*128) for these 128 q rows
    const int c0 = (qt + 1) * 128;
    if (c0 < S) {
        const f4v z = (f4v){0.f, 0.f, 0.f, 0.f};
        for (int r = w; r < 128; r += 8) {
            float* dst = attn_out + ((size_t)bh * S + qt * 128 + r) * S;
            for (int cc = c0 + lane * 4; cc < S; cc += 256)
                __builtin_nontemporal_store(z, (f4v*)(dst + cc));
        }
    }
#undef STAGEK
#undef LOADB
#undef QKT
#undef COMP_A
#undef LOADVr
#undef VSTORE
#undef COMP_B
#undef FLUSH2
}

extern "C" void kernel_launch(void* const* d_in, const int* in_sizes, int n_in,
                              void* d_out, int out_size, void* d_ws, size_t ws_size,
                              hipStream_t stream) {
    const float* x    = (const float*)d_in[0];
    const float* Wq   = (const float*)d_in[1];
    const float* Wk   = (const float*)d_in[2];
    const float* Wv   = (const float*)d_in[3];
    const float* Wo   = (const float*)d_in[4];
    const float* bias = (const float*)d_in[5];

    float* out  = (float*)d_out;                       // [2,2048,1024] f32
    float* attn = out + (size_t)2 * 2048 * 1024;       // [2,16,2048,2048] f32

    char* ws = (char*)d_ws;
    const size_t M1 = 1u << 20;
    short* x_bf    = (short*)ws;                       // 4M sh (reused as o_buf)
    short* wq_bf   = x_bf + 4 * M1;
    short* wk_bf   = wq_bf + M1;
    short* wv_bf   = wk_bf + M1;
    short* wo_bf   = wv_bf + M1;                       // ends 16MB
    short* bias_bf = wo_bf + M1;                       // 4M sh -> ends 24MB
    float* cosT    = (float*)(ws + 24 * M1);
    float* sinT    = cosT + 2048 * 64;                 // ends 25MB
    short* q_rope  = (short*)(ws + 25 * M1);
    short* k_rope  = q_rope + 4 * M1;
    short* v_bf    = k_rope + 4 * M1;                  // ends 49MB
    short* o_buf   = x_bf;                             // alias (x_bf dead after QKV)

    cast_kernel<<<6144, 256, 0, stream>>>(x, Wq, Wk, Wv, Wo, bias, x_bf, bias_bf);
    rope_table_kernel<<<512, 256, 0, stream>>>(cosT, sinT);
    gemm128<0><<<dim3(32, 8, 3), 256, 0, stream>>>(x_bf, wq_bf, wk_bf, wv_bf,
                                                   cosT, sinT, q_rope);
    attn_kernel<<<512, 512, 0, stream>>>(q_rope, k_rope, v_bf, bias_bf, attn, o_buf);
    gemm128<1><<<dim3(32, 8, 1), 256, 0, stream>>>(o_buf, wo_bf, wo_bf, wo_bf,
                                                   cosT, sinT, out);
}

// Round 18
// 244.590 us; speedup vs baseline: 1.0178x; 1.0178x over previous
//
#include <hip/hip_runtime.h>
#include <hip/hip_bf16.h>
#include <math.h>

// Shapes: B=2, S=2048, H=1024, nh=16, hd=64. Inputs f32, outputs f32.
// d_out = [out: 2*2048*1024] ++ [attn: 2*16*2048*2048], both f32.
// exp2-domain softmax, no running max. V stored PRE-TRANSPOSED [bh][d][s] by
// the QKV GEMM -> attn stages BOTH K and V via global_load_lds + XOR chunk
// swizzle (no reg->LDS transpose). P 2-slot LDS + in-loop NT flush,
// mask-free fast path + setprio, complementary qt pairing.

typedef __attribute__((ext_vector_type(8))) short bx8;   // 8 bf16 (4 VGPRs)
typedef __attribute__((ext_vector_type(4))) short sx4;   // 4 bf16
typedef __attribute__((ext_vector_type(4))) float fx4;   // MFMA accum
typedef __attribute__((ext_vector_type(4))) float f4v;

#define MFMA_BF16(a, b, c) __builtin_amdgcn_mfma_f32_16x16x32_bf16(a, b, c, 0, 0, 0)
#define LOG2E 1.44269504088896340736f

__device__ __forceinline__ short f2bf(float f) {
    union { float f; unsigned u; } v; v.f = f;
    unsigned u = v.u;
    u += 0x7fffu + ((u >> 16) & 1u);   // RTNE
    return (short)(u >> 16);
}
__device__ __forceinline__ float u2f(unsigned u) {
    union { unsigned u; float f; } v; v.u = u; return v.f;
}
__device__ __forceinline__ float bf2f(short s) {
    return u2f(((unsigned)(unsigned short)s) << 16);
}

__device__ __forceinline__ bx8 pack8(f4v a, f4v b) {
    bx8 r;
    r[0] = f2bf(a[0]); r[1] = f2bf(a[1]); r[2] = f2bf(a[2]); r[3] = f2bf(a[3]);
    r[4] = f2bf(b[0]); r[5] = f2bf(b[1]); r[6] = f2bf(b[2]); r[7] = f2bf(b[3]);
    return r;
}

__device__ __forceinline__ void gload_lds16(const short* g, short* l) {
    __builtin_amdgcn_global_load_lds(
        (const __attribute__((address_space(1))) void*)g,
        (__attribute__((address_space(3))) void*)l, 16, 0, 0);
}

// ---------------- cast: blocks 0..4095 -> bf16 of [x:4M][Wq..Wo:4x1M];
//                  blocks 4096..6143 -> bias_bf = bf16(bias * log2e)
__global__ __launch_bounds__(256) void cast_kernel(
        const float* __restrict__ x, const float* __restrict__ Wq,
        const float* __restrict__ Wk, const float* __restrict__ Wv,
        const float* __restrict__ Wo, const float* __restrict__ bias,
        short* __restrict__ dst, short* __restrict__ bias_bf)
{
    const size_t M1 = 1u << 20;
    if (blockIdx.x < 4096) {
        const size_t e0 = ((size_t)blockIdx.x * 256 + threadIdx.x) * 8;
        const float* src; size_t off;
        if (e0 < 4 * M1) { src = x; off = e0; }
        else {
            const int j = (int)((e0 - 4 * M1) >> 20);
            src = (j == 0) ? Wq : (j == 1) ? Wk : (j == 2) ? Wv : Wo;
            off = (e0 - 4 * M1) & (M1 - 1);
        }
        f4v a = *(const f4v*)(src + off);
        f4v b = *(const f4v*)(src + off + 4);
        *(bx8*)(dst + e0) = pack8(a, b);
    } else {
        const size_t e0 = ((size_t)(blockIdx.x - 4096) * 256 + threadIdx.x) * 8;
        f4v a = *(const f4v*)(bias + e0);
        f4v b = *(const f4v*)(bias + e0 + 4);
        #pragma unroll
        for (int i = 0; i < 4; ++i) { a[i] *= LOG2E; b[i] *= LOG2E; }
        *(bx8*)(bias_bf + e0) = pack8(a, b);
    }
}

// ---------------- RoPE cos/sin table: [2048][64] f32 each ----------------
__global__ void rope_table_kernel(float* __restrict__ cosT, float* __restrict__ sinT) {
    int i = blockIdx.x * 256 + threadIdx.x;
    if (i >= 2048 * 64) return;
    int s = i >> 6, d = i & 63;
    int fi = d & 31;                               // emb = concat(freqs, freqs)
    float inv_freq = powf(10000.0f, -(float)fi / 32.0f);
    float ang = (float)s * inv_freq;
    cosT[i] = cosf(ang);
    sinT[i] = sinf(ang);
}

// ---------------- GEMM 128x128, BK=64, global_load_lds + XOR chunk swizzle.
// OUTPROJ=0: epilogue staged through LDS Cs. z<=1: RoPE -> [bh][s][d] bf16
//            coalesced. z==2: V stored TRANSPOSED -> [bh][d][s] bf16.
// OUTPROJ=1: plain f32 row-major epilogue (direct stores).
template<int OUTPROJ>
__global__ __launch_bounds__(256) void gemm128(
        const short* __restrict__ A, const short* __restrict__ W0,
        const short* __restrict__ W1, const short* __restrict__ W2,
        const float* __restrict__ cosT, const float* __restrict__ sinT,
        void* __restrict__ Out)
{
    __shared__ __align__(16) char SMEM[128 * 130 * 2];   // 33280 B
    short (*As)[64]  = (short(*)[64])SMEM;               // 16 KB
    short (*Bs)[64]  = (short(*)[64])(SMEM + 16384);     // 16 KB
    short (*Cs)[130] = (short(*)[130])SMEM;              // epilogue alias

    const int bm = blockIdx.x, bn = blockIdx.y, z = blockIdx.z;
    const short* W = OUTPROJ ? W0 : (z == 0 ? W0 : (z == 1 ? W1 : W2));
    const int tid = threadIdx.x, w = tid >> 6, lane = tid & 63;
    const int cl = lane & 15, lg = lane >> 4;
    const int srow = lane >> 3;
    const int schunk = (lane & 7) ^ srow;

    fx4 acc[4][4];
    #pragma unroll
    for (int mi = 0; mi < 4; ++mi)
        #pragma unroll
        for (int ni = 0; ni < 4; ++ni) acc[mi][ni] = (fx4){0.f, 0.f, 0.f, 0.f};

    const int wr = (w >> 1) * 64, wc = (w & 1) * 64;

    for (int k0 = 0; k0 < 1024; k0 += 64) {
        __syncthreads();
        #pragma unroll
        for (int i = 0; i < 4; ++i) {
            const int rbase = w * 32 + i * 8;
            gload_lds16(A + (size_t)(bm * 128 + rbase + srow) * 1024 + k0 + schunk * 8,
                        &As[rbase][0]);
            gload_lds16(W + (size_t)(bn * 128 + rbase + srow) * 1024 + k0 + schunk * 8,
                        &Bs[rbase][0]);
        }
        __syncthreads();
        #pragma unroll
        for (int kk = 0; kk < 2; ++kk) {
            bx8 af[4], bf[4];
            #pragma unroll
            for (int i = 0; i < 4; ++i) {
                const int ra = wr + i * 16 + cl;
                af[i] = *(const bx8*)&As[ra][((kk * 4 + lg) ^ (ra & 7)) * 8];
                const int rb = wc + i * 16 + cl;
                bf[i] = *(const bx8*)&Bs[rb][((kk * 4 + lg) ^ (rb & 7)) * 8];
            }
            #pragma unroll
            for (int mi = 0; mi < 4; ++mi)
                #pragma unroll
                for (int ni = 0; ni < 4; ++ni)
                    acc[mi][ni] = MFMA_BF16(af[mi], bf[ni], acc[mi][ni]);
        }
    }

    if constexpr (OUTPROJ) {
        #pragma unroll
        for (int mi = 0; mi < 4; ++mi) {
            #pragma unroll
            for (int reg = 0; reg < 4; ++reg) {
                const int r = bm * 128 + wr + mi * 16 + (lg << 2) + reg;
                #pragma unroll
                for (int ni = 0; ni < 4; ++ni) {
                    const int col = bn * 128 + wc + ni * 16 + cl;
                    ((float*)Out)[(size_t)r * 1024 + col] = acc[mi][ni][reg];
                }
            }
        }
    } else {
        __syncthreads();                    // all waves done reading As/Bs
        #pragma unroll
        for (int mi = 0; mi < 4; ++mi) {
            #pragma unroll
            for (int reg = 0; reg < 4; ++reg) {
                const int rl = wr + mi * 16 + (lg << 2) + reg;   // local row
                const int s = (bm * 128 + rl) & 2047;
                #pragma unroll
                for (int ni = 0; ni < 4; ++ni) {
                    const int cloc = wc + ni * 16 + cl;          // local col
                    const int d = cloc & 63;
                    float v = acc[mi][ni][reg];
                    if (z <= 1) {
                        const float cs = cosT[s * 64 + d], sn = sinT[s * 64 + d];
                        const float partner = acc[mi][ni ^ 2][reg];   // d ^ 32
                        const float rot = (d < 32) ? -partner : partner;
                        v = v * cs + rot * sn;
                        if (z == 0) v *= 0.125f * LOG2E;   // scale+exp2 fold into q
                    }
                    Cs[rl][cloc] = f2bf(v);
                }
            }
        }
        __syncthreads();                    // Cs complete
        if (z == 2) {
            // V^T store: unit = (hh, d, 8-s chunk); 8 per thread.
            // Each wave-store = 8 x 128B fully-utilized segments of [bh][d][s].
            #pragma unroll
            for (int i = 0; i < 8; ++i) {
                const int u = tid + i * 256;
                const int c = u & 15, d = (u >> 4) & 63, hh = u >> 10;
                bx8 vv;
                #pragma unroll
                for (int j = 0; j < 8; ++j) vv[j] = Cs[c * 8 + j][hh * 64 + d];
                const int r0 = bm * 128 + c * 8;
                const int bb = r0 >> 11, ss = r0 & 2047;
                short* dst = (short*)Out + (size_t)2 * 32 * 2048 * 64
                           + ((size_t)(bb * 16 + bn * 2 + hh) * 64 + d) * 2048 + ss;
                *(bx8*)dst = vv;
            }
        } else {
            // q/k store: unit = (s_local, h, 16B-chunk); 8 per thread.
            #pragma unroll
            for (int i = 0; i < 8; ++i) {
                const int u = tid + i * 256;
                const int chunk = u & 7, hh = (u >> 3) & 1, sl = u >> 4;
                bx8 vv = *(const bx8*)&Cs[sl][hh * 64 + chunk * 8];
                const int r = bm * 128 + sl;
                const int bb = r >> 11, ss = r & 2047;
                short* dst = (short*)Out + (size_t)z * 32 * 2048 * 64
                           + (size_t)((bb * 16 + bn * 2 + hh) * 2048 + ss) * 64 + chunk * 8;
                *(bx8*)dst = vv;
            }
        }
    }
}

// ---------------- Attention: QBLK=128, 512 thr (8 waves x 16 q-rows),
// grid 512, complementary qt pairing. NT = 2qt+2 (even). K AND V both staged
// via gload_lds + XOR chunk swizzle (V is pre-transposed [bh][d][s]).
// LDS 66.8KB -> 2 blocks/CU. Mask-free fast path + setprio.
__global__ __launch_bounds__(512, 4) void attn_kernel(
        const short* __restrict__ Q, const short* __restrict__ K,
        const short* __restrict__ Vt_g, const short* __restrict__ bias_bf,
        float* __restrict__ attn_out, short* __restrict__ o_buf)
{
    const int S = 2048;
    const int bid = blockIdx.x;                    // 0..511
    const int bh = (bid & 7) * 4 + ((bid >> 3) & 3);   // same for bid, bid+256
    const int qt = (bid < 256) ? (15 - (bid >> 5)) : ((bid >> 5) - 8);
    const int h = bh & 15, b = bh >> 4;
    const int tid = threadIdx.x, w = tid >> 6, lane = tid & 63;
    const int cl = lane & 15, lg = lane >> 4;
    const size_t base = (size_t)bh * S * 64;
    const size_t vbase = (size_t)bh * 64 * S;      // V^T [d][s]
    const int NT = 2 * qt + 2;                     // always even

    __shared__ short Ks[2][64][64];    // K tile [kc][d], XOR-chunk swizzled
    __shared__ short Vt[2][64][64];    // V^T tile [d][kc], XOR-chunk swizzled
    __shared__ short P[8][16][136];    // per-wave P, 2 tile-slots

    const int krow8 = lane >> 3, kchk = (lane & 7) ^ krow8;

    const short* qp = Q + base + (size_t)(qt * 128 + w * 16 + cl) * 64 + lg * 8;
    const bx8 qf0 = *(const bx8*)qp;
    const bx8 qf1 = *(const bx8*)(qp + 32);
    const int qr  = qt * 128 + w * 16 + cl;          // lane's q row
    const int qrmin = qt * 128 + w * 16;             // wave's min q row
    const int sq0 = qt * 128 + w * 16 + (lg << 2);   // lane's first O row
    const short* brow = bias_bf + (size_t)qr * 2048;
    const size_t strip_base = ((size_t)bh * S + qt * 128 + w * 16) * S;

#define STAGEK(BUF, t)                                                            \
    gload_lds16(K + base + (size_t)((t) * 64 + w * 8 + krow8) * 64 + kchk * 8,    \
                &Ks[BUF][w * 8][0]);

#define STAGEV(BUF, t)                                                            \
    gload_lds16(Vt_g + vbase + (size_t)(w * 8 + krow8) * 2048 + (t) * 64 + kchk * 8, \
                &Vt[BUF][w * 8][0]);

#define LOADB(BR, t)                                                              \
    { _Pragma("unroll") for (int n = 0; n < 4; ++n)                               \
        BR[n] = *(const sx4*)(brow + (t) * 64 + n * 16 + (lg << 2)); }

#define QKT(BUF, SACC)                                                            \
    { const int cs_ = cl & 7;                                                     \
      const fx4 zf = (fx4){0.f, 0.f, 0.f, 0.f};                                   \
      __builtin_amdgcn_s_setprio(1);                                              \
      _Pragma("unroll") for (int n = 0; n < 4; ++n) {                             \
        bx8 a0 = *(const bx8*)&Ks[BUF][n * 16 + cl][(lg ^ cs_) * 8];              \
        bx8 a1 = *(const bx8*)&Ks[BUF][n * 16 + cl][((4 + lg) ^ cs_) * 8];        \
        SACC[n] = MFMA_BF16(a0, qf0, zf);                                         \
        SACC[n] = MFMA_BF16(a1, qf1, SACC[n]); }                                  \
      __builtin_amdgcn_s_setprio(0); }

#define COMP_A(BUF, BR, t)                                                        \
    { fx4 sacc[4]; QKT(BUF, sacc);                                                \
      if ((t) * 64 + 63 <= qrmin) {               /* fully causal: no mask */     \
        _Pragma("unroll") for (int n = 0; n < 4; ++n)                             \
          _Pragma("unroll") for (int e = 0; e < 4; ++e)                           \
            lsum[n] += exp2f(sacc[n][e] + bf2f(BR[n][e]));                        \
      } else {                                                                    \
        _Pragma("unroll") for (int n = 0; n < 4; ++n)                             \
          _Pragma("unroll") for (int e = 0; e < 4; ++e) {                         \
            const int kc = (t) * 64 + n * 16 + (lg << 2) + e;                     \
            const float sv = sacc[n][e] + bf2f(BR[n][e]);                         \
            lsum[n] += (kc <= qr) ? exp2f(sv) : 0.f; }                            \
      } }

#define COMP_B(KBUF, BR, VBUF, t)                                                 \
    { fx4 sacc[4]; QKT(KBUF, sacc);                                               \
      if ((t) * 64 + 63 <= qrmin) {               /* fully causal: no mask */     \
        _Pragma("unroll") for (int n = 0; n < 4; ++n) {                           \
          sx4 pb;                                                                 \
          _Pragma("unroll") for (int e = 0; e < 4; ++e)                           \
            pb[e] = f2bf(exp2f(sacc[n][e] + bf2f(BR[n][e]) - L2));                \
          *(sx4*)&P[w][cl][((t) & 1) * 64 + n * 16 + (lg << 2)] = pb; }           \
      } else {                                                                    \
        _Pragma("unroll") for (int n = 0; n < 4; ++n) {                           \
          sx4 pb;                                                                 \
          _Pragma("unroll") for (int e = 0; e < 4; ++e) {                         \
            const int kc = (t) * 64 + n * 16 + (lg << 2) + e;                     \
            const float sv = sacc[n][e] + bf2f(BR[n][e]);                         \
            const float p = (kc <= qr) ? exp2f(sv - L2) : 0.f;                    \
            pb[e] = f2bf(p); }                                                    \
          *(sx4*)&P[w][cl][((t) & 1) * 64 + n * 16 + (lg << 2)] = pb; }           \
      }                                                                           \
      __builtin_amdgcn_s_setprio(1);                                              \
      { const int cs_ = cl & 7;                                                   \
        _Pragma("unroll") for (int kk = 0; kk < 2; ++kk) {                        \
          bx8 pa = *(const bx8*)&P[w][cl][((t) & 1) * 64 + kk * 32 + lg * 8];     \
          _Pragma("unroll") for (int n = 0; n < 4; ++n) {                         \
            const int R = n * 16 + cl;                                            \
            bx8 vb = *(const bx8*)&Vt[VBUF][R][(((kk * 4 + lg)) ^ (R & 7)) * 8];  \
            oacc[n] = MFMA_BF16(pa, vb, oacc[n]); } } }                           \
      __builtin_amdgcn_s_setprio(0); }

#define FLUSH2(tp)                                                                \
    { _Pragma("unroll") for (int rp = 0; rp < 16; rp += 2) {                      \
        const int row = rp + (lane >> 5), col = (lane & 31) * 4;                  \
        const unsigned* ps = (const unsigned*)&P[w][row][col];                    \
        const unsigned px = ps[0], py = ps[1];                                    \
        f4v o; o[0] = u2f(px << 16); o[1] = u2f(px & 0xffff0000u);                \
        o[2] = u2f(py << 16); o[3] = u2f(py & 0xffff0000u);                       \
        __builtin_nontemporal_store(o,                                            \
            (f4v*)(attn_out + strip_base + (size_t)row * S + (tp) * 64 + col)); } }

    float lsum[4] = {0.f, 0.f, 0.f, 0.f};

    // ---- PASS A: l = sum exp2(s2+bias); staged K, NT even -> no tail ----
    {
        sx4 bA[4], bB[4];
        STAGEK(0, 0); LOADB(bA, 0);
        __syncthreads();
        for (int t = 0; t + 1 < NT; t += 2) {
            STAGEK(1, t + 1); LOADB(bB, t + 1);
            COMP_A(0, bA, t);
            __syncthreads();
            if (t + 2 < NT) { STAGEK(0, t + 2); LOADB(bA, t + 2); }
            COMP_A(1, bB, t + 1);
            __syncthreads();
        }
    }

    float l = (lsum[0] + lsum[1]) + (lsum[2] + lsum[3]);
    l += __shfl_xor(l, 16);
    l += __shfl_xor(l, 32);
    const float L2 = __log2f(l);

    fx4 oacc[4];
    #pragma unroll
    for (int n = 0; n < 4; n++) oacc[n] = (fx4){0.f, 0.f, 0.f, 0.f};

    // ---- PASS B ----
    sx4 bA[4], bB[4];
    STAGEK(0, 0); STAGEV(0, 0); LOADB(bA, 0);
    __syncthreads();                   // K/V tile 0 staged
    for (int t = 0; t + 1 < NT; t += 2) {
        STAGEK(1, t + 1); STAGEV(1, t + 1); LOADB(bB, t + 1);
        COMP_B(0, bA, 0, t);
        __syncthreads();
        if (t + 2 < NT) { STAGEK(0, t + 2); STAGEV(0, t + 2); LOADB(bA, t + 2); }
        COMP_B(1, bB, 1, t + 1);
        FLUSH2(t);                     // wave-local P -> attn, cols t*64..t*64+127
        __syncthreads();
    }

    // write O tile to o_buf[b][s][h*64+d] (bf16; re-read by outproj)
    #pragma unroll
    for (int reg = 0; reg < 4; reg++) {
        const int sq = sq0 + reg;
        #pragma unroll
        for (int n = 0; n < 4; n++) {
            const int d = n * 16 + cl;
            o_buf[(size_t)(b * 2048 + sq) * 1024 + h * 64 + d] = f2bf(oacc[n][reg]);
        }
    }

    // zero-fill strict upper triangle (k >= (qt+1)*128) for these 128 q rows
    const int c0 = (qt + 1) * 128;
    if (c0 < S) {
        const f4v z = (f4v){0.f, 0.f, 0.f, 0.f};
        for (int r = w; r < 128; r += 8) {
            float* dst = attn_out + ((size_t)bh * S + qt * 128 + r) * S;
            for (int cc = c0 + lane * 4; cc < S; cc += 256)
                __builtin_nontemporal_store(z, (f4v*)(dst + cc));
        }
    }
#undef STAGEK
#undef STAGEV
#undef LOADB
#undef QKT
#undef COMP_A
#undef COMP_B
#undef FLUSH2
}

extern "C" void kernel_launch(void* const* d_in, const int* in_sizes, int n_in,
                              void* d_out, int out_size, void* d_ws, size_t ws_size,
                              hipStream_t stream) {
    const float* x    = (const float*)d_in[0];
    const float* Wq   = (const float*)d_in[1];
    const float* Wk   = (const float*)d_in[2];
    const float* Wv   = (const float*)d_in[3];
    const float* Wo   = (const float*)d_in[4];
    const float* bias = (const float*)d_in[5];

    float* out  = (float*)d_out;                       // [2,2048,1024] f32
    float* attn = out + (size_t)2 * 2048 * 1024;       // [2,16,2048,2048] f32

    char* ws = (char*)d_ws;
    const size_t M1 = 1u << 20;
    short* x_bf    = (short*)ws;                       // 4M sh (reused as o_buf)
    short* wq_bf   = x_bf + 4 * M1;
    short* wk_bf   = wq_bf + M1;
    short* wv_bf   = wk_bf + M1;
    short* wo_bf   = wv_bf + M1;                       // ends 16MB
    short* bias_bf = wo_bf + M1;                       // 4M sh -> ends 24MB
    float* cosT    = (float*)(ws + 24 * M1);
    float* sinT    = cosT + 2048 * 64;                 // ends 25MB
    short* q_rope  = (short*)(ws + 25 * M1);
    short* k_rope  = q_rope + 4 * M1;
    short* vT_bf   = k_rope + 4 * M1;                  // [bh][d][s], ends 49MB
    short* o_buf   = x_bf;                             // alias (x_bf dead after QKV)

    cast_kernel<<<6144, 256, 0, stream>>>(x, Wq, Wk, Wv, Wo, bias, x_bf, bias_bf);
    rope_table_kernel<<<512, 256, 0, stream>>>(cosT, sinT);
    gemm128<0><<<dim3(32, 8, 3), 256, 0, stream>>>(x_bf, wq_bf, wk_bf, wv_bf,
                                                   cosT, sinT, q_rope);
    attn_kernel<<<512, 512, 0, stream>>>(q_rope, k_rope, vT_bf, bias_bf, attn, o_buf);
    gemm128<1><<<dim3(32, 8, 1), 256, 0, stream>>>(o_buf, wo_bf, wo_bf, wo_bf,
                                                   cosT, sinT, out);
}

// Round 19
// 242.871 us; speedup vs baseline: 1.0250x; 1.0071x over previous
//
#include <hip/hip_runtime.h>
#include <hip/hip_bf16.h>
#include <math.h>

// Shapes: B=2, S=2048, H=1024, nh=16, hd=64. Inputs f32, outputs f32.
// d_out = [out: 2*2048*1024] ++ [attn: 2*16*2048*2048], both f32.
// exp2-domain softmax, no running max. V pre-transposed [bh][d][s]; K and V
// both staged via gload_lds + XOR chunk swizzle. Bias (and -L2 in pass B)
// folded into the MFMA C-operand -> softmax chain is mfma->exp2 only.

typedef __attribute__((ext_vector_type(8))) short bx8;   // 8 bf16 (4 VGPRs)
typedef __attribute__((ext_vector_type(4))) short sx4;   // 4 bf16
typedef __attribute__((ext_vector_type(4))) float fx4;   // MFMA accum
typedef __attribute__((ext_vector_type(4))) float f4v;

#define MFMA_BF16(a, b, c) __builtin_amdgcn_mfma_f32_16x16x32_bf16(a, b, c, 0, 0, 0)
#define LOG2E 1.44269504088896340736f

__device__ __forceinline__ short f2bf(float f) {
    union { float f; unsigned u; } v; v.f = f;
    unsigned u = v.u;
    u += 0x7fffu + ((u >> 16) & 1u);   // RTNE
    return (short)(u >> 16);
}
__device__ __forceinline__ float u2f(unsigned u) {
    union { unsigned u; float f; } v; v.u = u; return v.f;
}
__device__ __forceinline__ float bf2f(short s) {
    return u2f(((unsigned)(unsigned short)s) << 16);
}

__device__ __forceinline__ bx8 pack8(f4v a, f4v b) {
    bx8 r;
    r[0] = f2bf(a[0]); r[1] = f2bf(a[1]); r[2] = f2bf(a[2]); r[3] = f2bf(a[3]);
    r[4] = f2bf(b[0]); r[5] = f2bf(b[1]); r[6] = f2bf(b[2]); r[7] = f2bf(b[3]);
    return r;
}

__device__ __forceinline__ void gload_lds16(const short* g, short* l) {
    __builtin_amdgcn_global_load_lds(
        (const __attribute__((address_space(1))) void*)g,
        (__attribute__((address_space(3))) void*)l, 16, 0, 0);
}

// ---------------- cast: blocks 0..4095 -> bf16 of [x:4M][Wq..Wo:4x1M];
//                  blocks 4096..6143 -> bias_bf = bf16(bias * log2e)
__global__ __launch_bounds__(256) void cast_kernel(
        const float* __restrict__ x, const float* __restrict__ Wq,
        const float* __restrict__ Wk, const float* __restrict__ Wv,
        const float* __restrict__ Wo, const float* __restrict__ bias,
        short* __restrict__ dst, short* __restrict__ bias_bf)
{
    const size_t M1 = 1u << 20;
    if (blockIdx.x < 4096) {
        const size_t e0 = ((size_t)blockIdx.x * 256 + threadIdx.x) * 8;
        const float* src; size_t off;
        if (e0 < 4 * M1) { src = x; off = e0; }
        else {
            const int j = (int)((e0 - 4 * M1) >> 20);
            src = (j == 0) ? Wq : (j == 1) ? Wk : (j == 2) ? Wv : Wo;
            off = (e0 - 4 * M1) & (M1 - 1);
        }
        f4v a = *(const f4v*)(src + off);
        f4v b = *(const f4v*)(src + off + 4);
        *(bx8*)(dst + e0) = pack8(a, b);
    } else {
        const size_t e0 = ((size_t)(blockIdx.x - 4096) * 256 + threadIdx.x) * 8;
        f4v a = *(const f4v*)(bias + e0);
        f4v b = *(const f4v*)(bias + e0 + 4);
        #pragma unroll
        for (int i = 0; i < 4; ++i) { a[i] *= LOG2E; b[i] *= LOG2E; }
        *(bx8*)(bias_bf + e0) = pack8(a, b);
    }
}

// ---------------- RoPE cos/sin table: [2048][64] f32 each ----------------
__global__ void rope_table_kernel(float* __restrict__ cosT, float* __restrict__ sinT) {
    int i = blockIdx.x * 256 + threadIdx.x;
    if (i >= 2048 * 64) return;
    int s = i >> 6, d = i & 63;
    int fi = d & 31;                               // emb = concat(freqs, freqs)
    float inv_freq = powf(10000.0f, -(float)fi / 32.0f);
    float ang = (float)s * inv_freq;
    cosT[i] = cosf(ang);
    sinT[i] = sinf(ang);
}

// ---------------- GEMM 128x128, BK=64, global_load_lds + XOR chunk swizzle.
// OUTPROJ=0: epilogue staged through LDS Cs. z<=1: RoPE -> [bh][s][d] bf16
//            coalesced. z==2: V stored TRANSPOSED -> [bh][d][s] bf16.
// OUTPROJ=1: plain f32 row-major epilogue (direct stores).
template<int OUTPROJ>
__global__ __launch_bounds__(256) void gemm128(
        const short* __restrict__ A, const short* __restrict__ W0,
        const short* __restrict__ W1, const short* __restrict__ W2,
        const float* __restrict__ cosT, const float* __restrict__ sinT,
        void* __restrict__ Out)
{
    __shared__ __align__(16) char SMEM[128 * 130 * 2];   // 33280 B
    short (*As)[64]  = (short(*)[64])SMEM;               // 16 KB
    short (*Bs)[64]  = (short(*)[64])(SMEM + 16384);     // 16 KB
    short (*Cs)[130] = (short(*)[130])SMEM;              // epilogue alias

    const int bm = blockIdx.x, bn = blockIdx.y, z = blockIdx.z;
    const short* W = OUTPROJ ? W0 : (z == 0 ? W0 : (z == 1 ? W1 : W2));
    const int tid = threadIdx.x, w = tid >> 6, lane = tid & 63;
    const int cl = lane & 15, lg = lane >> 4;
    const int srow = lane >> 3;
    const int schunk = (lane & 7) ^ srow;

    fx4 acc[4][4];
    #pragma unroll
    for (int mi = 0; mi < 4; ++mi)
        #pragma unroll
        for (int ni = 0; ni < 4; ++ni) acc[mi][ni] = (fx4){0.f, 0.f, 0.f, 0.f};

    const int wr = (w >> 1) * 64, wc = (w & 1) * 64;

    for (int k0 = 0; k0 < 1024; k0 += 64) {
        __syncthreads();
        #pragma unroll
        for (int i = 0; i < 4; ++i) {
            const int rbase = w * 32 + i * 8;
            gload_lds16(A + (size_t)(bm * 128 + rbase + srow) * 1024 + k0 + schunk * 8,
                        &As[rbase][0]);
            gload_lds16(W + (size_t)(bn * 128 + rbase + srow) * 1024 + k0 + schunk * 8,
                        &Bs[rbase][0]);
        }
        __syncthreads();
        #pragma unroll
        for (int kk = 0; kk < 2; ++kk) {
            bx8 af[4], bf[4];
            #pragma unroll
            for (int i = 0; i < 4; ++i) {
                const int ra = wr + i * 16 + cl;
                af[i] = *(const bx8*)&As[ra][((kk * 4 + lg) ^ (ra & 7)) * 8];
                const int rb = wc + i * 16 + cl;
                bf[i] = *(const bx8*)&Bs[rb][((kk * 4 + lg) ^ (rb & 7)) * 8];
            }
            #pragma unroll
            for (int mi = 0; mi < 4; ++mi)
                #pragma unroll
                for (int ni = 0; ni < 4; ++ni)
                    acc[mi][ni] = MFMA_BF16(af[mi], bf[ni], acc[mi][ni]);
        }
    }

    if constexpr (OUTPROJ) {
        #pragma unroll
        for (int mi = 0; mi < 4; ++mi) {
            #pragma unroll
            for (int reg = 0; reg < 4; ++reg) {
                const int r = bm * 128 + wr + mi * 16 + (lg << 2) + reg;
                #pragma unroll
                for (int ni = 0; ni < 4; ++ni) {
                    const int col = bn * 128 + wc + ni * 16 + cl;
                    ((float*)Out)[(size_t)r * 1024 + col] = acc[mi][ni][reg];
                }
            }
        }
    } else {
        __syncthreads();                    // all waves done reading As/Bs
        #pragma unroll
        for (int mi = 0; mi < 4; ++mi) {
            #pragma unroll
            for (int reg = 0; reg < 4; ++reg) {
                const int rl = wr + mi * 16 + (lg << 2) + reg;   // local row
                const int s = (bm * 128 + rl) & 2047;
                #pragma unroll
                for (int ni = 0; ni < 4; ++ni) {
                    const int cloc = wc + ni * 16 + cl;          // local col
                    const int d = cloc & 63;
                    float v = acc[mi][ni][reg];
                    if (z <= 1) {
                        const float cs = cosT[s * 64 + d], sn = sinT[s * 64 + d];
                        const float partner = acc[mi][ni ^ 2][reg];   // d ^ 32
                        const float rot = (d < 32) ? -partner : partner;
                        v = v * cs + rot * sn;
                        if (z == 0) v *= 0.125f * LOG2E;   // scale+exp2 fold into q
                    }
                    Cs[rl][cloc] = f2bf(v);
                }
            }
        }
        __syncthreads();                    // Cs complete
        if (z == 2) {
            // V^T store: unit = (hh, d, 8-s chunk); 8 per thread.
            #pragma unroll
            for (int i = 0; i < 8; ++i) {
                const int u = tid + i * 256;
                const int c = u & 15, d = (u >> 4) & 63, hh = u >> 10;
                bx8 vv;
                #pragma unroll
                for (int j = 0; j < 8; ++j) vv[j] = Cs[c * 8 + j][hh * 64 + d];
                const int r0 = bm * 128 + c * 8;
                const int bb = r0 >> 11, ss = r0 & 2047;
                short* dst = (short*)Out + (size_t)2 * 32 * 2048 * 64
                           + ((size_t)(bb * 16 + bn * 2 + hh) * 64 + d) * 2048 + ss;
                *(bx8*)dst = vv;
            }
        } else {
            // q/k store: unit = (s_local, h, 16B-chunk); 8 per thread.
            #pragma unroll
            for (int i = 0; i < 8; ++i) {
                const int u = tid + i * 256;
                const int chunk = u & 7, hh = (u >> 3) & 1, sl = u >> 4;
                bx8 vv = *(const bx8*)&Cs[sl][hh * 64 + chunk * 8];
                const int r = bm * 128 + sl;
                const int bb = r >> 11, ss = r & 2047;
                short* dst = (short*)Out + (size_t)z * 32 * 2048 * 64
                           + (size_t)((bb * 16 + bn * 2 + hh) * 2048 + ss) * 64 + chunk * 8;
                *(bx8*)dst = vv;
            }
        }
    }
}

// ---------------- Attention: QBLK=128, 512 thr (8 waves x 16 q-rows),
// grid 512, complementary qt pairing. NT = 2qt+2 (even). K AND V staged via
// gload_lds + XOR chunk swizzle. Bias (and -L2 in pass B) folded into the
// MFMA C-operand. LDS 66.8KB -> 2 blocks/CU. Mask-free fast path + setprio.
__global__ __launch_bounds__(512, 4) void attn_kernel(
        const short* __restrict__ Q, const short* __restrict__ K,
        const short* __restrict__ Vt_g, const short* __restrict__ bias_bf,
        float* __restrict__ attn_out, short* __restrict__ o_buf)
{
    const int S = 2048;
    const int bid = blockIdx.x;                    // 0..511
    const int bh = (bid & 7) * 4 + ((bid >> 3) & 3);   // same for bid, bid+256
    const int qt = (bid < 256) ? (15 - (bid >> 5)) : ((bid >> 5) - 8);
    const int h = bh & 15, b = bh >> 4;
    const int tid = threadIdx.x, w = tid >> 6, lane = tid & 63;
    const int cl = lane & 15, lg = lane >> 4;
    const size_t base = (size_t)bh * S * 64;
    const size_t vbase = (size_t)bh * 64 * S;      // V^T [d][s]
    const int NT = 2 * qt + 2;                     // always even

    __shared__ short Ks[2][64][64];    // K tile [kc][d], XOR-chunk swizzled
    __shared__ short Vt[2][64][64];    // V^T tile [d][kc], XOR-chunk swizzled
    __shared__ short P[8][16][136];    // per-wave P, 2 tile-slots

    const int krow8 = lane >> 3, kchk = (lane & 7) ^ krow8;

    const short* qp = Q + base + (size_t)(qt * 128 + w * 16 + cl) * 64 + lg * 8;
    const bx8 qf0 = *(const bx8*)qp;
    const bx8 qf1 = *(const bx8*)(qp + 32);
    const int qr  = qt * 128 + w * 16 + cl;          // lane's q row
    const int qrmin = qt * 128 + w * 16;             // wave's min q row
    const int sq0 = qt * 128 + w * 16 + (lg << 2);   // lane's first O row
    const short* brow = bias_bf + (size_t)qr * 2048;
    const size_t strip_base = ((size_t)bh * S + qt * 128 + w * 16) * S;

#define STAGEK(BUF, t)                                                            \
    gload_lds16(K + base + (size_t)((t) * 64 + w * 8 + krow8) * 64 + kchk * 8,    \
                &Ks[BUF][w * 8][0]);

#define STAGEV(BUF, t)                                                            \
    gload_lds16(Vt_g + vbase + (size_t)(w * 8 + krow8) * 2048 + (t) * 64 + kchk * 8, \
                &Vt[BUF][w * 8][0]);

#define LOADB(BR, t)                                                              \
    { _Pragma("unroll") for (int n = 0; n < 4; ++n)                               \
        BR[n] = *(const sx4*)(brow + (t) * 64 + n * 16 + (lg << 2)); }

// QK^T with C-operand CARR (bias, optionally minus L2) pre-loaded.
#define QKT_C(BUF, CARR, SACC)                                                    \
    { const int cs_ = cl & 7;                                                     \
      __builtin_amdgcn_s_setprio(1);                                              \
      _Pragma("unroll") for (int n = 0; n < 4; ++n) {                             \
        bx8 a0 = *(const bx8*)&Ks[BUF][n * 16 + cl][(lg ^ cs_) * 8];              \
        bx8 a1 = *(const bx8*)&Ks[BUF][n * 16 + cl][((4 + lg) ^ cs_) * 8];        \
        SACC[n] = MFMA_BF16(a0, qf0, CARR[n]);                                    \
        SACC[n] = MFMA_BF16(a1, qf1, SACC[n]); }                                  \
      __builtin_amdgcn_s_setprio(0); }

#define COMP_A(BUF, BR, t)                                                        \
    { fx4 c[4];                                                                   \
      _Pragma("unroll") for (int n = 0; n < 4; ++n)                               \
        _Pragma("unroll") for (int e = 0; e < 4; ++e) c[n][e] = bf2f(BR[n][e]);   \
      fx4 sacc[4]; QKT_C(BUF, c, sacc);                                           \
      if ((t) * 64 + 63 <= qrmin) {               /* fully causal: no mask */     \
        _Pragma("unroll") for (int n = 0; n < 4; ++n)                             \
          _Pragma("unroll") for (int e = 0; e < 4; ++e)                           \
            lsum[n] += exp2f(sacc[n][e]);                                         \
      } else {                                                                    \
        _Pragma("unroll") for (int n = 0; n < 4; ++n)                             \
          _Pragma("unroll") for (int e = 0; e < 4; ++e) {                         \
            const int kc = (t) * 64 + n * 16 + (lg << 2) + e;                     \
            lsum[n] += (kc <= qr) ? exp2f(sacc[n][e]) : 0.f; }                    \
      } }

#define COMP_B(KBUF, BR, VBUF, t)                                                 \
    { fx4 c[4];                                                                   \
      _Pragma("unroll") for (int n = 0; n < 4; ++n)                               \
        _Pragma("unroll") for (int e = 0; e < 4; ++e)                             \
          c[n][e] = bf2f(BR[n][e]) - L2;                                          \
      fx4 sacc[4]; QKT_C(KBUF, c, sacc);                                          \
      if ((t) * 64 + 63 <= qrmin) {               /* fully causal: no mask */     \
        _Pragma("unroll") for (int n = 0; n < 4; ++n) {                           \
          sx4 pb;                                                                 \
          _Pragma("unroll") for (int e = 0; e < 4; ++e)                           \
            pb[e] = f2bf(exp2f(sacc[n][e]));                                      \
          *(sx4*)&P[w][cl][((t) & 1) * 64 + n * 16 + (lg << 2)] = pb; }           \
      } else {                                                                    \
        _Pragma("unroll") for (int n = 0; n < 4; ++n) {                           \
          sx4 pb;                                                                 \
          _Pragma("unroll") for (int e = 0; e < 4; ++e) {                         \
            const int kc = (t) * 64 + n * 16 + (lg << 2) + e;                     \
            const float p = (kc <= qr) ? exp2f(sacc[n][e]) : 0.f;                 \
            pb[e] = f2bf(p); }                                                    \
          *(sx4*)&P[w][cl][((t) & 1) * 64 + n * 16 + (lg << 2)] = pb; }           \
      }                                                                           \
      __builtin_amdgcn_s_setprio(1);                                              \
      { const int cs_ = cl & 7;                                                   \
        _Pragma("unroll") for (int kk = 0; kk < 2; ++kk) {                        \
          bx8 pa = *(const bx8*)&P[w][cl][((t) & 1) * 64 + kk * 32 + lg * 8];     \
          _Pragma("unroll") for (int n = 0; n < 4; ++n) {                         \
            const int R = n * 16 + cl;                                            \
            bx8 vb = *(const bx8*)&Vt[VBUF][R][(((kk * 4 + lg)) ^ (R & 7)) * 8];  \
            oacc[n] = MFMA_BF16(pa, vb, oacc[n]); } } }                           \
      __builtin_amdgcn_s_setprio(0); }

#define FLUSH2(tp)                                                                \
    { _Pragma("unroll") for (int rp = 0; rp < 16; rp += 2) {                      \
        const int row = rp + (lane >> 5), col = (lane & 31) * 4;                  \
        const unsigned* ps = (const unsigned*)&P[w][row][col];                    \
        const unsigned px = ps[0], py = ps[1];                                    \
        f4v o; o[0] = u2f(px << 16); o[1] = u2f(px & 0xffff0000u);                \
        o[2] = u2f(py << 16); o[3] = u2f(py & 0xffff0000u);                       \
        __builtin_nontemporal_store(o,                                            \
            (f4v*)(attn_out + strip_base + (size_t)row * S + (tp) * 64 + col)); } }

    float lsum[4] = {0.f, 0.f, 0.f, 0.f};

    // ---- PASS A: l = sum exp2(s2+bias); staged K, NT even -> no tail ----
    {
        sx4 bA[4], bB[4];
        STAGEK(0, 0); LOADB(bA, 0);
        __syncthreads();
        for (int t = 0; t + 1 < NT; t += 2) {
            STAGEK(1, t + 1); LOADB(bB, t + 1);
            COMP_A(0, bA, t);
            __syncthreads();
            if (t + 2 < NT) { STAGEK(0, t + 2); LOADB(bA, t + 2); }
            COMP_A(1, bB, t + 1);
            __syncthreads();
        }
    }

    float l = (lsum[0] + lsum[1]) + (lsum[2] + lsum[3]);
    l += __shfl_xor(l, 16);
    l += __shfl_xor(l, 32);
    const float L2 = __log2f(l);

    fx4 oacc[4];
    #pragma unroll
    for (int n = 0; n < 4; n++) oacc[n] = (fx4){0.f, 0.f, 0.f, 0.f};

    // ---- PASS B ----
    sx4 bA[4], bB[4];
    STAGEK(0, 0); STAGEV(0, 0); LOADB(bA, 0);
    __syncthreads();                   // K/V tile 0 staged
    for (int t = 0; t + 1 < NT; t += 2) {
        STAGEK(1, t + 1); STAGEV(1, t + 1); LOADB(bB, t + 1);
        COMP_B(0, bA, 0, t);
        __syncthreads();
        if (t + 2 < NT) { STAGEK(0, t + 2); STAGEV(0, t + 2); LOADB(bA, t + 2); }
        COMP_B(1, bB, 1, t + 1);
        FLUSH2(t);                     // wave-local P -> attn, cols t*64..t*64+127
        __syncthreads();
    }

    // write O tile to o_buf[b][s][h*64+d] (bf16; re-read by outproj)
    #pragma unroll
    for (int reg = 0; reg < 4; reg++) {
        const int sq = sq0 + reg;
        #pragma unroll
        for (int n = 0; n < 4; n++) {
            const int d = n * 16 + cl;
            o_buf[(size_t)(b * 2048 + sq) * 1024 + h * 64 + d] = f2bf(oacc[n][reg]);
        }
    }

    // zero-fill strict upper triangle (k >= (qt+1)*128) for these 128 q rows
    const int c0 = (qt + 1) * 128;
    if (c0 < S) {
        const f4v z = (f4v){0.f, 0.f, 0.f, 0.f};
        for (int r = w; r < 128; r += 8) {
            float* dst = attn_out + ((size_t)bh * S + qt * 128 + r) * S;
            for (int cc = c0 + lane * 4; cc < S; cc += 256)
                __builtin_nontemporal_store(z, (f4v*)(dst + cc));
        }
    }
#undef STAGEK
#undef STAGEV
#undef LOADB
#undef QKT_C
#undef COMP_A
#undef COMP_B
#undef FLUSH2
}

extern "C" void kernel_launch(void* const* d_in, const int* in_sizes, int n_in,
                              void* d_out, int out_size, void* d_ws, size_t ws_size,
                              hipStream_t stream) {
    const float* x    = (const float*)d_in[0];
    const float* Wq   = (const float*)d_in[1];
    const float* Wk   = (const float*)d_in[2];
    const float* Wv   = (const float*)d_in[3];
    const float* Wo   = (const float*)d_in[4];
    const float* bias = (const float*)d_in[5];

    float* out  = (float*)d_out;                       // [2,2048,1024] f32
    float* attn = out + (size_t)2 * 2048 * 1024;       // [2,16,2048,2048] f32

    char* ws = (char*)d_ws;
    const size_t M1 = 1u << 20;
    short* x_bf    = (short*)ws;                       // 4M sh (reused as o_buf)
    short* wq_bf   = x_bf + 4 * M1;
    short* wk_bf   = wq_bf + M1;
    short* wv_bf   = wk_bf + M1;
    short* wo_bf   = wv_bf + M1;                       // ends 16MB
    short* bias_bf = wo_bf + M1;                       // 4M sh -> ends 24MB
    float* cosT    = (float*)(ws + 24 * M1);
    float* sinT    = cosT + 2048 * 64;                 // ends 25MB
    short* q_rope  = (short*)(ws + 25 * M1);
    short* k_rope  = q_rope + 4 * M1;
    short* vT_bf   = k_rope + 4 * M1;                  // [bh][d][s], ends 49MB
    short* o_buf   = x_bf;                             // alias (x_bf dead after QKV)

    cast_kernel<<<6144, 256, 0, stream>>>(x, Wq, Wk, Wv, Wo, bias, x_bf, bias_bf);
    rope_table_kernel<<<512, 256, 0, stream>>>(cosT, sinT);
    gemm128<0><<<dim3(32, 8, 3), 256, 0, stream>>>(x_bf, wq_bf, wk_bf, wv_bf,
                                                   cosT, sinT, q_rope);
    attn_kernel<<<512, 512, 0, stream>>>(q_rope, k_rope, vT_bf, bias_bf, attn, o_buf);
    gemm128<1><<<dim3(32, 8, 1), 256, 0, stream>>>(o_buf, wo_bf, wo_bf, wo_bf,
                                                   cosT, sinT, out);
}